// Round 1
// baseline (10600.266 us; speedup 1.0000x reference)
//
#include <hip/hip_runtime.h>
#include <hip/hip_bf16.h>
#include <math.h>

typedef __hip_bfloat16 bf16;

__device__ __forceinline__ float blo(unsigned u){ union{unsigned i; float f;} v; v.i = u << 16; return v.f; }
__device__ __forceinline__ float bhi(unsigned u){ union{unsigned i; float f;} v; v.i = u & 0xffff0000u; return v.f; }
__device__ __forceinline__ bf16 f2b(float v){ return __float2bfloat16(v); }
__device__ __forceinline__ float b2f(bf16 v){ return __bfloat162float(v); }
__device__ __forceinline__ float gelu_exact(float v){ return 0.5f * v * (1.f + erff(v * 0.70710678118654752f)); }

// ============================================================================
// Kernel A: per-window fused LN1 + shifted-window attention + proj + residual.
// One block = one 4x4x4 window (64 tokens, C=96). Grid = 4096.
// Gathers tokens directly from their FINAL positions (roll(+2) of reversed
// coords == source positions under roll(-2)), so window_partition/reverse and
// both rolls are free.
// ============================================================================
__global__ __launch_bounds__(256)
void swin_attn_kernel(const float* __restrict__ x,
                      const float* __restrict__ ln1_w, const float* __restrict__ ln1_b,
                      const float* __restrict__ qkv_w, const float* __restrict__ qkv_b,
                      const float* __restrict__ proj_w, const float* __restrict__ proj_b,
                      float* __restrict__ x2)
{
    __shared__ int tok_off[64];
    __shared__ __align__(16) bf16 ln_s[64][104];  // LN1 output, bf16, 16B-aligned rows
    __shared__ __align__(16) bf16 qh[64][34];     // per-head q (scaled)
    __shared__ __align__(16) bf16 kh[64][34];
    __shared__ __align__(16) bf16 vh[64][34];
    __shared__ __align__(16) float S[64][65];     // scores / probs, fp32
    __shared__ __align__(16) bf16 ao[64][104];    // attention output (all heads)

    const int tid = threadIdx.x;
    const int win = blockIdx.x;
    const int b  = win >> 11;        // 2048 windows per batch (8*16*16)
    const int wd = (win >> 8) & 7;
    const int wh = (win >> 4) & 15;
    const int ww = win & 15;

    if (tid < 64) {
        const int n  = tid;
        const int df = (wd*4 + (n >> 4)       + 2) & 31;
        const int hf = (wh*4 + ((n >> 2) & 3) + 2) & 63;
        const int wf = (ww*4 + (n & 3)        + 2) & 63;
        tok_off[n] = (((b*32 + df)*64 + hf)*64 + wf) * 96;
    }
    __syncthreads();

    // ---- LN1: 4 lanes per token (wave-local), fp32 stats ----
    {
        const int lane = tid & 63;
        const int n    = (tid >> 6)*16 + (lane >> 2);
        const int sub  = lane & 3;
        const float4* xr4 = (const float4*)(x + tok_off[n] + sub*24);
        float4 va[6];
        float s = 0.f, ss = 0.f;
        #pragma unroll
        for (int i = 0; i < 6; i++) {
            va[i] = xr4[i];
            s  += va[i].x + va[i].y + va[i].z + va[i].w;
            ss += va[i].x*va[i].x + va[i].y*va[i].y + va[i].z*va[i].z + va[i].w*va[i].w;
        }
        s += __shfl_xor(s, 1); ss += __shfl_xor(ss, 1);
        s += __shfl_xor(s, 2); ss += __shfl_xor(ss, 2);
        const float mean = s * (1.f/96.f);
        const float var  = ss * (1.f/96.f) - mean*mean;
        const float inv  = rsqrtf(var + 1e-5f);
        #pragma unroll
        for (int i = 0; i < 6; i++) {
            const float vv[4] = {va[i].x, va[i].y, va[i].z, va[i].w};
            #pragma unroll
            for (int j2 = 0; j2 < 4; j2++) {
                const int c = sub*24 + i*4 + j2;
                ln_s[n][c] = f2b((vv[j2] - mean) * inv * ln1_w[c] + ln1_b[c]);
            }
        }
    }
    __syncthreads();

    // Cache this thread's ln row (token tid&63) in registers: 12 x (8 bf16)
    uint4 lreg[12];
    {
        const uint4* lr = (const uint4*)&ln_s[tid & 63][0];
        #pragma unroll
        for (int cc = 0; cc < 12; cc++) lreg[cc] = lr[cc];
    }

    for (int h = 0; h < 3; h++) {
        // ---- QKV for this head: thread = (token n = tid&63, quarter q4) ----
        {
            const int n  = tid & 63;
            const int q4 = tid >> 6;
            for (int i = 0; i < 24; i++) {
                const int jj = q4*24 + i;      // 0..95: [q|k|v] x 32 dims
                const int m  = jj >> 5;
                const int dd = jj & 31;
                const int j  = m*96 + h*32 + dd;
                const float4* wr = (const float4*)(qkv_w + j*96);  // wave-uniform row
                float acc = 0.f;
                #pragma unroll
                for (int cc = 0; cc < 12; cc++) {
                    const uint4 a = lreg[cc];
                    const float4 w0 = wr[cc*2], w1 = wr[cc*2 + 1];
                    acc = fmaf(blo(a.x), w0.x, acc);
                    acc = fmaf(bhi(a.x), w0.y, acc);
                    acc = fmaf(blo(a.y), w0.z, acc);
                    acc = fmaf(bhi(a.y), w0.w, acc);
                    acc = fmaf(blo(a.z), w1.x, acc);
                    acc = fmaf(bhi(a.z), w1.y, acc);
                    acc = fmaf(blo(a.w), w1.z, acc);
                    acc = fmaf(bhi(a.w), w1.w, acc);
                }
                acc += qkv_b[j];
                if (m == 0)      qh[n][dd] = f2b(acc * 0.17677669529663688f); // * hd^-0.5
                else if (m == 1) kh[n][dd] = f2b(acc);
                else             vh[n][dd] = f2b(acc);
            }
        }
        __syncthreads();

        // ---- scores S[n][m2] = q.k ----
        for (int k = 0; k < 16; k++) {
            const int oi = tid + (k << 8);
            const int n  = oi >> 6;
            const int m2 = oi & 63;
            float acc = 0.f;
            #pragma unroll
            for (int d2 = 0; d2 < 16; d2++) {
                const unsigned qv = *(const unsigned*)&qh[n][d2*2];
                const unsigned kv = *(const unsigned*)&kh[m2][d2*2];
                acc = fmaf(blo(qv), blo(kv), acc);
                acc = fmaf(bhi(qv), bhi(kv), acc);
            }
            S[n][m2] = acc;
        }
        __syncthreads();

        // ---- softmax per row: 4 lanes per row ----
        {
            const int lane = tid & 63;
            const int n    = (tid >> 6)*16 + (lane >> 2);
            const int sub  = lane & 3;
            float e[16];
            float mx = -1e30f;
            #pragma unroll
            for (int i = 0; i < 16; i++) { e[i] = S[n][sub*16 + i]; mx = fmaxf(mx, e[i]); }
            mx = fmaxf(mx, __shfl_xor(mx, 1));
            mx = fmaxf(mx, __shfl_xor(mx, 2));
            float sum = 0.f;
            #pragma unroll
            for (int i = 0; i < 16; i++) { e[i] = __expf(e[i] - mx); sum += e[i]; }
            sum += __shfl_xor(sum, 1);
            sum += __shfl_xor(sum, 2);
            const float r = 1.f / sum;
            #pragma unroll
            for (int i = 0; i < 16; i++) S[n][sub*16 + i] = e[i] * r;
        }
        __syncthreads();

        // ---- PV: each thread does 4 (token, dd-pair) outputs ----
        for (int k = 0; k < 4; k++) {
            const int oi  = tid + (k << 8);
            const int n   = oi >> 4;
            const int ddp = oi & 15;
            float acc0 = 0.f, acc1 = 0.f;
            #pragma unroll 8
            for (int m2 = 0; m2 < 64; m2++) {
                const unsigned vv = *(const unsigned*)&vh[m2][ddp*2];
                const float p = S[n][m2];
                acc0 = fmaf(p, blo(vv), acc0);
                acc1 = fmaf(p, bhi(vv), acc1);
            }
            ao[n][h*32 + ddp*2]     = f2b(acc0);
            ao[n][h*32 + ddp*2 + 1] = f2b(acc1);
        }
        __syncthreads();
    }

    // ---- proj + residual: 4 lanes per token, coalesced-ish 16B writes ----
    {
        const int pn   = tid >> 2;
        const int psub = tid & 3;
        uint4 areg[12];
        const uint4* ar = (const uint4*)&ao[pn][0];
        #pragma unroll
        for (int cc = 0; cc < 12; cc++) areg[cc] = ar[cc];
        const int toff = tok_off[pn];
        for (int i = 0; i < 24; i++) {
            const int c = 4*i + psub;
            const float4* wr = (const float4*)(proj_w + c*96);
            float acc = proj_b[c];
            #pragma unroll
            for (int cc = 0; cc < 12; cc++) {
                const uint4 a = areg[cc];
                const float4 w0 = wr[cc*2], w1 = wr[cc*2 + 1];
                acc = fmaf(blo(a.x), w0.x, acc);
                acc = fmaf(bhi(a.x), w0.y, acc);
                acc = fmaf(blo(a.y), w0.z, acc);
                acc = fmaf(bhi(a.y), w0.w, acc);
                acc = fmaf(blo(a.z), w1.x, acc);
                acc = fmaf(bhi(a.z), w1.y, acc);
                acc = fmaf(blo(a.w), w1.z, acc);
                acc = fmaf(bhi(a.w), w1.w, acc);
            }
            x2[toff + c] = x[toff + c] + acc;
        }
    }
}

// ============================================================================
// Kernel B: in-place LN2 + FC1 + exact GELU + FC2 + residual on d_out.
// One block = 16 tokens. Grid = 16384.
// ============================================================================
__global__ __launch_bounds__(256)
void swin_mlp_kernel(float* __restrict__ io,
                     const float* __restrict__ ln2_w, const float* __restrict__ ln2_b,
                     const float* __restrict__ fc1_w, const float* __restrict__ fc1_b,
                     const float* __restrict__ fc2_w, const float* __restrict__ fc2_b)
{
    __shared__ float x2s[16][97];
    __shared__ __align__(16) float ln2s[16][100];
    __shared__ __align__(16) float hid[16][388];
    const int tid = threadIdx.x;
    const long long base = (long long)blockIdx.x * (16*96);

    // ---- LN2: 16 lanes per token ----
    {
        const int lane = tid & 63;
        const int t    = (tid >> 6)*4 + (lane >> 4);
        const int sub  = lane & 15;
        const float2* xr2 = (const float2*)(io + base + t*96 + sub*6);
        const float2 a0 = xr2[0], a1 = xr2[1], a2 = xr2[2];
        float s  = a0.x + a0.y + a1.x + a1.y + a2.x + a2.y;
        float ss = a0.x*a0.x + a0.y*a0.y + a1.x*a1.x + a1.y*a1.y + a2.x*a2.x + a2.y*a2.y;
        #pragma unroll
        for (int m = 1; m < 16; m <<= 1) { s += __shfl_xor(s, m); ss += __shfl_xor(ss, m); }
        const float mean = s * (1.f/96.f);
        const float var  = ss * (1.f/96.f) - mean*mean;
        const float inv  = rsqrtf(var + 1e-5f);
        const float vv[6] = {a0.x, a0.y, a1.x, a1.y, a2.x, a2.y};
        #pragma unroll
        for (int i2 = 0; i2 < 6; i2++) {
            const int c = sub*6 + i2;
            x2s[t][c]  = vv[i2];
            ln2s[t][c] = (vv[i2] - mean) * inv * ln2_w[c] + ln2_b[c];
        }
    }
    __syncthreads();

    // ---- FC1 + GELU: 16 lanes per token, 4 rows per group ----
    {
        const int tt = tid >> 4;
        const int jl = tid & 15;
        const float4* lr = (const float4*)&ln2s[tt][0];
        for (int g = 0; g < 6; g++) {
            const int j0 = jl + 64*g;
            const float4* w0 = (const float4*)(fc1_w + j0*96);
            const float4* w1 = (const float4*)(fc1_w + (j0+16)*96);
            const float4* w2 = (const float4*)(fc1_w + (j0+32)*96);
            const float4* w3 = (const float4*)(fc1_w + (j0+48)*96);
            float a0 = fc1_b[j0], a1 = fc1_b[j0+16], a2 = fc1_b[j0+32], a3 = fc1_b[j0+48];
            #pragma unroll
            for (int cc = 0; cc < 24; cc++) {
                const float4 l = lr[cc];
                float4 p;
                p = w0[cc]; a0 = fmaf(l.x,p.x, fmaf(l.y,p.y, fmaf(l.z,p.z, fmaf(l.w,p.w, a0))));
                p = w1[cc]; a1 = fmaf(l.x,p.x, fmaf(l.y,p.y, fmaf(l.z,p.z, fmaf(l.w,p.w, a1))));
                p = w2[cc]; a2 = fmaf(l.x,p.x, fmaf(l.y,p.y, fmaf(l.z,p.z, fmaf(l.w,p.w, a2))));
                p = w3[cc]; a3 = fmaf(l.x,p.x, fmaf(l.y,p.y, fmaf(l.z,p.z, fmaf(l.w,p.w, a3))));
            }
            hid[tt][j0]    = gelu_exact(a0);
            hid[tt][j0+16] = gelu_exact(a1);
            hid[tt][j0+32] = gelu_exact(a2);
            hid[tt][j0+48] = gelu_exact(a3);
        }
    }
    __syncthreads();

    // ---- FC2 + residual (in-place write) ----
    {
        const int tt = tid >> 4;
        const int cl = tid & 15;
        const float4* hr = (const float4*)&hid[tt][0];
        for (int g = 0; g < 2; g++) {
            const int c0 = cl + 48*g;
            const float4* w0 = (const float4*)(fc2_w + c0*384);
            const float4* w1 = (const float4*)(fc2_w + (c0+16)*384);
            const float4* w2 = (const float4*)(fc2_w + (c0+32)*384);
            float a0 = fc2_b[c0], a1 = fc2_b[c0+16], a2 = fc2_b[c0+32];
            #pragma unroll 8
            for (int jj = 0; jj < 96; jj++) {
                const float4 hv = hr[jj];
                float4 p;
                p = w0[jj]; a0 = fmaf(hv.x,p.x, fmaf(hv.y,p.y, fmaf(hv.z,p.z, fmaf(hv.w,p.w, a0))));
                p = w1[jj]; a1 = fmaf(hv.x,p.x, fmaf(hv.y,p.y, fmaf(hv.z,p.z, fmaf(hv.w,p.w, a1))));
                p = w2[jj]; a2 = fmaf(hv.x,p.x, fmaf(hv.y,p.y, fmaf(hv.z,p.z, fmaf(hv.w,p.w, a2))));
            }
            io[base + tt*96 + c0]    = x2s[tt][c0]    + a0;
            io[base + tt*96 + c0+16] = x2s[tt][c0+16] + a1;
            io[base + tt*96 + c0+32] = x2s[tt][c0+32] + a2;
        }
    }
}

extern "C" void kernel_launch(void* const* d_in, const int* in_sizes, int n_in,
                              void* d_out, int out_size, void* d_ws, size_t ws_size,
                              hipStream_t stream)
{
    const float* x      = (const float*)d_in[0];
    const float* ln1_w  = (const float*)d_in[1];
    const float* ln1_b  = (const float*)d_in[2];
    const float* qkv_w  = (const float*)d_in[3];
    const float* qkv_b  = (const float*)d_in[4];
    const float* proj_w = (const float*)d_in[5];
    const float* proj_b = (const float*)d_in[6];
    const float* ln2_w  = (const float*)d_in[7];
    const float* ln2_b  = (const float*)d_in[8];
    const float* fc1_w  = (const float*)d_in[9];
    const float* fc1_b  = (const float*)d_in[10];
    const float* fc2_w  = (const float*)d_in[11];
    const float* fc2_b  = (const float*)d_in[12];
    float* out = (float*)d_out;

    swin_attn_kernel<<<4096, 256, 0, stream>>>(x, ln1_w, ln1_b, qkv_w, qkv_b,
                                               proj_w, proj_b, out);
    swin_mlp_kernel<<<16384, 256, 0, stream>>>(out, ln2_w, ln2_b, fc1_w, fc1_b,
                                               fc2_w, fc2_b);
}

// Round 3
// 2691.088 us; speedup vs baseline: 3.9390x; 3.9390x over previous
//
#include <hip/hip_runtime.h>
#include <hip/hip_bf16.h>
#include <math.h>

typedef __hip_bfloat16 bf16;
using short8 = __attribute__((ext_vector_type(8))) short;
using f32x4  = __attribute__((ext_vector_type(4))) float;

__device__ __forceinline__ float blo(unsigned u){ union{unsigned i; float f;} v; v.i = u << 16; return v.f; }
__device__ __forceinline__ float bhi(unsigned u){ union{unsigned i; float f;} v; v.i = u & 0xffff0000u; return v.f; }
__device__ __forceinline__ bf16 f2b(float v){ return __float2bfloat16(v); }
__device__ __forceinline__ float gelu_exact(float v){ return 0.5f * v * (1.f + erff(v * 0.70710678118654752f)); }

// ============================================================================
// Weight prep: fp32 weights -> bf16 B-fragment layout for mfma_f32_16x16x32_bf16.
// Fragment f=(nt,kt): lane l, elem i holds W[nt*16+(l&15)][kt*32+8*(l>>4)+i].
// Stored at dst[f*512 + l*8 + i] so each lane loads one contiguous 16B uint4.
// ws layout (bf16 elems): qkv @0 (54 frags), proj @27648 (18), fc1 @36864 (72),
// fc2 @73728 (72). Total 110592 bf16 = 216 KiB.
// ============================================================================
__global__ __launch_bounds__(256)
void prep_weights(const float* __restrict__ qkv_w, const float* __restrict__ proj_w,
                  const float* __restrict__ fc1_w, const float* __restrict__ fc2_w,
                  bf16* __restrict__ ws)
{
    const int t = blockIdx.x * 256 + threadIdx.x;
    const int f = t >> 6;
    const int lane = t & 63;
    const float* W; int KT, fr; bf16* dst;
    if (f < 54)       { W = qkv_w;  KT = 3;  fr = f;       dst = ws; }
    else if (f < 72)  { W = proj_w; KT = 3;  fr = f - 54;  dst = ws + 54*512; }
    else if (f < 144) { W = fc1_w;  KT = 3;  fr = f - 72;  dst = ws + 72*512; }
    else              { W = fc2_w;  KT = 12; fr = f - 144; dst = ws + 144*512; }
    const int nt = fr / KT, kt = fr % KT;
    const int Kin = KT * 32;
    const float* src = W + (nt*16 + (lane & 15))*Kin + kt*32 + 8*(lane >> 4);
    bf16* d = dst + fr*512 + lane*8;
    #pragma unroll
    for (int i = 0; i < 8; i++) d[i] = f2b(src[i]);
}

// ============================================================================
// Kernel A: per-window fused LN1 + shifted-window attention + proj + residual.
// (unchanged from R1 — correct, ~2.5ms; MFMA rewrite next round)
// ============================================================================
__global__ __launch_bounds__(256)
void swin_attn_kernel(const float* __restrict__ x,
                      const float* __restrict__ ln1_w, const float* __restrict__ ln1_b,
                      const float* __restrict__ qkv_w, const float* __restrict__ qkv_b,
                      const float* __restrict__ proj_w, const float* __restrict__ proj_b,
                      float* __restrict__ x2)
{
    __shared__ int tok_off[64];
    __shared__ __align__(16) bf16 ln_s[64][104];
    __shared__ __align__(16) bf16 qh[64][34];
    __shared__ __align__(16) bf16 kh[64][34];
    __shared__ __align__(16) bf16 vh[64][34];
    __shared__ __align__(16) float S[64][65];
    __shared__ __align__(16) bf16 ao[64][104];

    const int tid = threadIdx.x;
    const int win = blockIdx.x;
    const int b  = win >> 11;
    const int wd = (win >> 8) & 7;
    const int wh = (win >> 4) & 15;
    const int ww = win & 15;

    if (tid < 64) {
        const int n  = tid;
        const int df = (wd*4 + (n >> 4)       + 2) & 31;
        const int hf = (wh*4 + ((n >> 2) & 3) + 2) & 63;
        const int wf = (ww*4 + (n & 3)        + 2) & 63;
        tok_off[n] = (((b*32 + df)*64 + hf)*64 + wf) * 96;
    }
    __syncthreads();

    {
        const int lane = tid & 63;
        const int n    = (tid >> 6)*16 + (lane >> 2);
        const int sub  = lane & 3;
        const float4* xr4 = (const float4*)(x + tok_off[n] + sub*24);
        float4 va[6];
        float s = 0.f, ss = 0.f;
        #pragma unroll
        for (int i = 0; i < 6; i++) {
            va[i] = xr4[i];
            s  += va[i].x + va[i].y + va[i].z + va[i].w;
            ss += va[i].x*va[i].x + va[i].y*va[i].y + va[i].z*va[i].z + va[i].w*va[i].w;
        }
        s += __shfl_xor(s, 1); ss += __shfl_xor(ss, 1);
        s += __shfl_xor(s, 2); ss += __shfl_xor(ss, 2);
        const float mean = s * (1.f/96.f);
        const float var  = ss * (1.f/96.f) - mean*mean;
        const float inv  = rsqrtf(var + 1e-5f);
        #pragma unroll
        for (int i = 0; i < 6; i++) {
            const float vv[4] = {va[i].x, va[i].y, va[i].z, va[i].w};
            #pragma unroll
            for (int j2 = 0; j2 < 4; j2++) {
                const int c = sub*24 + i*4 + j2;
                ln_s[n][c] = f2b((vv[j2] - mean) * inv * ln1_w[c] + ln1_b[c]);
            }
        }
    }
    __syncthreads();

    uint4 lreg[12];
    {
        const uint4* lr = (const uint4*)&ln_s[tid & 63][0];
        #pragma unroll
        for (int cc = 0; cc < 12; cc++) lreg[cc] = lr[cc];
    }

    for (int h = 0; h < 3; h++) {
        {
            const int n  = tid & 63;
            const int q4 = tid >> 6;
            for (int i = 0; i < 24; i++) {
                const int jj = q4*24 + i;
                const int m  = jj >> 5;
                const int dd = jj & 31;
                const int j  = m*96 + h*32 + dd;
                const float4* wr = (const float4*)(qkv_w + j*96);
                float acc = 0.f;
                #pragma unroll
                for (int cc = 0; cc < 12; cc++) {
                    const uint4 a = lreg[cc];
                    const float4 w0 = wr[cc*2], w1 = wr[cc*2 + 1];
                    acc = fmaf(blo(a.x), w0.x, acc);
                    acc = fmaf(bhi(a.x), w0.y, acc);
                    acc = fmaf(blo(a.y), w0.z, acc);
                    acc = fmaf(bhi(a.y), w0.w, acc);
                    acc = fmaf(blo(a.z), w1.x, acc);
                    acc = fmaf(bhi(a.z), w1.y, acc);
                    acc = fmaf(blo(a.w), w1.z, acc);
                    acc = fmaf(bhi(a.w), w1.w, acc);
                }
                acc += qkv_b[j];
                if (m == 0)      qh[n][dd] = f2b(acc * 0.17677669529663688f);
                else if (m == 1) kh[n][dd] = f2b(acc);
                else             vh[n][dd] = f2b(acc);
            }
        }
        __syncthreads();

        for (int k = 0; k < 16; k++) {
            const int oi = tid + (k << 8);
            const int n  = oi >> 6;
            const int m2 = oi & 63;
            float acc = 0.f;
            #pragma unroll
            for (int d2 = 0; d2 < 16; d2++) {
                const unsigned qv = *(const unsigned*)&qh[n][d2*2];
                const unsigned kv = *(const unsigned*)&kh[m2][d2*2];
                acc = fmaf(blo(qv), blo(kv), acc);
                acc = fmaf(bhi(qv), bhi(kv), acc);
            }
            S[n][m2] = acc;
        }
        __syncthreads();

        {
            const int lane = tid & 63;
            const int n    = (tid >> 6)*16 + (lane >> 2);
            const int sub  = lane & 3;
            float e[16];
            float mx = -1e30f;
            #pragma unroll
            for (int i = 0; i < 16; i++) { e[i] = S[n][sub*16 + i]; mx = fmaxf(mx, e[i]); }
            mx = fmaxf(mx, __shfl_xor(mx, 1));
            mx = fmaxf(mx, __shfl_xor(mx, 2));
            float sum = 0.f;
            #pragma unroll
            for (int i = 0; i < 16; i++) { e[i] = __expf(e[i] - mx); sum += e[i]; }
            sum += __shfl_xor(sum, 1);
            sum += __shfl_xor(sum, 2);
            const float r = 1.f / sum;
            #pragma unroll
            for (int i = 0; i < 16; i++) S[n][sub*16 + i] = e[i] * r;
        }
        __syncthreads();

        for (int k = 0; k < 4; k++) {
            const int oi  = tid + (k << 8);
            const int n   = oi >> 4;
            const int ddp = oi & 15;
            float acc0 = 0.f, acc1 = 0.f;
            #pragma unroll 8
            for (int m2 = 0; m2 < 64; m2++) {
                const unsigned vv = *(const unsigned*)&vh[m2][ddp*2];
                const float p = S[n][m2];
                acc0 = fmaf(p, blo(vv), acc0);
                acc1 = fmaf(p, bhi(vv), acc1);
            }
            ao[n][h*32 + ddp*2]     = f2b(acc0);
            ao[n][h*32 + ddp*2 + 1] = f2b(acc1);
        }
        __syncthreads();
    }

    {
        const int pn   = tid >> 2;
        const int psub = tid & 3;
        uint4 areg[12];
        const uint4* ar = (const uint4*)&ao[pn][0];
        #pragma unroll
        for (int cc = 0; cc < 12; cc++) areg[cc] = ar[cc];
        const int toff = tok_off[pn];
        for (int i = 0; i < 24; i++) {
            const int c = 4*i + psub;
            const float4* wr = (const float4*)(proj_w + c*96);
            float acc = proj_b[c];
            #pragma unroll
            for (int cc = 0; cc < 12; cc++) {
                const uint4 a = areg[cc];
                const float4 w0 = wr[cc*2], w1 = wr[cc*2 + 1];
                acc = fmaf(blo(a.x), w0.x, acc);
                acc = fmaf(bhi(a.x), w0.y, acc);
                acc = fmaf(blo(a.y), w0.z, acc);
                acc = fmaf(bhi(a.y), w0.w, acc);
                acc = fmaf(blo(a.z), w1.x, acc);
                acc = fmaf(bhi(a.z), w1.y, acc);
                acc = fmaf(blo(a.w), w1.z, acc);
                acc = fmaf(bhi(a.w), w1.w, acc);
            }
            x2[toff + c] = x[toff + c] + acc;
        }
    }
}

// ============================================================================
// Kernel B (MFMA): in-place LN2 + FC1 + exact GELU + FC2 + residual.
// Block = 64 tokens, 4 waves; wave w owns token rows w*16..w*16+15.
// FC1: 24 n-tiles x 3 MFMA(16x16x32 bf16); FC2: 6 n-tiles x 12 MFMA.
// C/D mapping: col = lane&15, row = (lane>>4)*4 + reg (HW-verified m89/m91).
// ============================================================================
__global__ __launch_bounds__(256)
void swin_mlp_mfma(float* __restrict__ io,
                   const float* __restrict__ ln2_w, const float* __restrict__ ln2_b,
                   const float* __restrict__ fc1_b, const float* __restrict__ fc2_b,
                   const bf16* __restrict__ wsf)
{
    __shared__ __align__(16) bf16 ln2s[64][104];   // 13.0 KiB (stride 208B: 2-way max)
    __shared__ __align__(16) bf16 hid[64][392];    // 49.0 KiB (stride 784B: 2-way max)

    const int tid = threadIdx.x;
    const long long base = (long long)blockIdx.x * (64*96);
    const bf16* w1f = wsf + 72*512;    // fc1 frags
    const bf16* w2f = wsf + 144*512;   // fc2 frags

    // ---- LN2: 4 lanes per token ----
    {
        const int lane = tid & 63;
        const int n    = (tid >> 6)*16 + (lane >> 2);
        const int sub  = lane & 3;
        const float4* xr4 = (const float4*)(io + base + n*96 + sub*24);
        float4 va[6];
        float s = 0.f, ss = 0.f;
        #pragma unroll
        for (int i = 0; i < 6; i++) {
            va[i] = xr4[i];
            s  += va[i].x + va[i].y + va[i].z + va[i].w;
            ss += va[i].x*va[i].x + va[i].y*va[i].y + va[i].z*va[i].z + va[i].w*va[i].w;
        }
        s += __shfl_xor(s, 1); ss += __shfl_xor(ss, 1);
        s += __shfl_xor(s, 2); ss += __shfl_xor(ss, 2);
        const float mean = s * (1.f/96.f);
        const float var  = ss * (1.f/96.f) - mean*mean;
        const float inv  = rsqrtf(var + 1e-5f);
        #pragma unroll
        for (int i = 0; i < 6; i++) {
            const float vv[4] = {va[i].x, va[i].y, va[i].z, va[i].w};
            #pragma unroll
            for (int j2 = 0; j2 < 4; j2++) {
                const int c = sub*24 + i*4 + j2;
                ln2s[n][c] = f2b((vv[j2] - mean) * inv * ln2_w[c] + ln2_b[c]);
            }
        }
    }
    __syncthreads();

    const int w    = tid >> 6;
    const int lane = tid & 63;
    const int m0   = w * 16;
    const int lc   = lane & 15;     // col within 16x16 tile
    const int lr   = lane >> 4;     // row group
    const int tokr = m0 + lr*4;     // +reg -> token row

    // ---- FC1 + GELU -> hid ----
    {
        short8 afr[3];
        #pragma unroll
        for (int kt = 0; kt < 3; kt++)
            afr[kt] = *(const short8*)&ln2s[m0 + lc][kt*32 + 8*lr];

        for (int nt = 0; nt < 24; nt++) {
            f32x4 acc = {0.f, 0.f, 0.f, 0.f};
            #pragma unroll
            for (int kt = 0; kt < 3; kt++) {
                const short8 bfr = *(const short8*)(w1f + (nt*3 + kt)*512 + lane*8);
                acc = __builtin_amdgcn_mfma_f32_16x16x32_bf16(afr[kt], bfr, acc, 0, 0, 0);
            }
            const int j = nt*16 + lc;
            const float bias = fc1_b[j];
            #pragma unroll
            for (int r = 0; r < 4; r++)
                hid[tokr + r][j] = f2b(gelu_exact(acc[r] + bias));
        }
    }
    __syncthreads();

    // ---- FC2 + bias + residual (in-place) ----
    {
        short8 afr[12];
        #pragma unroll
        for (int kt = 0; kt < 12; kt++)
            afr[kt] = *(const short8*)&hid[m0 + lc][kt*32 + 8*lr];

        for (int nt = 0; nt < 6; nt++) {
            f32x4 acc = {0.f, 0.f, 0.f, 0.f};
            #pragma unroll
            for (int kt = 0; kt < 12; kt++) {
                const short8 bfr = *(const short8*)(w2f + (nt*12 + kt)*512 + lane*8);
                acc = __builtin_amdgcn_mfma_f32_16x16x32_bf16(afr[kt], bfr, acc, 0, 0, 0);
            }
            const int j = nt*16 + lc;
            const float bias = fc2_b[j];
            #pragma unroll
            for (int r = 0; r < 4; r++) {
                const long long off = base + (long long)(tokr + r)*96 + j;
                io[off] = io[off] + acc[r] + bias;
            }
        }
    }
}

extern "C" void kernel_launch(void* const* d_in, const int* in_sizes, int n_in,
                              void* d_out, int out_size, void* d_ws, size_t ws_size,
                              hipStream_t stream)
{
    const float* x      = (const float*)d_in[0];
    const float* ln1_w  = (const float*)d_in[1];
    const float* ln1_b  = (const float*)d_in[2];
    const float* qkv_w  = (const float*)d_in[3];
    const float* qkv_b  = (const float*)d_in[4];
    const float* proj_w = (const float*)d_in[5];
    const float* proj_b = (const float*)d_in[6];
    const float* ln2_w  = (const float*)d_in[7];
    const float* ln2_b  = (const float*)d_in[8];
    const float* fc1_w  = (const float*)d_in[9];
    const float* fc1_b  = (const float*)d_in[10];
    const float* fc2_w  = (const float*)d_in[11];
    const float* fc2_b  = (const float*)d_in[12];
    float* out = (float*)d_out;
    bf16* wsf  = (bf16*)d_ws;   // needs 216 KiB

    prep_weights<<<54, 256, 0, stream>>>(qkv_w, proj_w, fc1_w, fc2_w, wsf);
    swin_attn_kernel<<<4096, 256, 0, stream>>>(x, ln1_w, ln1_b, qkv_w, qkv_b,
                                               proj_w, proj_b, out);
    swin_mlp_mfma<<<4096, 256, 0, stream>>>(out, ln2_w, ln2_b, fc1_b, fc2_b, wsf);
}

// Round 4
// 428.165 us; speedup vs baseline: 24.7574x; 6.2852x over previous
//
#include <hip/hip_runtime.h>
#include <hip/hip_bf16.h>
#include <math.h>

typedef __hip_bfloat16 bf16;
using short8 = __attribute__((ext_vector_type(8))) short;
using f32x4  = __attribute__((ext_vector_type(4))) float;

__device__ __forceinline__ bf16 f2b(float v){ return __float2bfloat16(v); }
__device__ __forceinline__ float gelu_exact(float v){ return 0.5f * v * (1.f + erff(v * 0.70710678118654752f)); }

// ============================================================================
// Weight prep: fp32 weights -> bf16 fragment layout for mfma_f32_16x16x32_bf16.
// Fragment f=(nt,kt): lane l, elem i holds W[nt*16+(l&15)][kt*32+8*(l>>4)+i],
// stored at dst[f*512 + l*8 + i] (one contiguous 16B load per lane).
// These bits serve as B-frags (W as right operand: D = X·W^T tile) AND as
// A-frags (W rows as left operand) — layouts coincide.
// ws layout (bf16): qkv @0 (54 frags), proj @54*512 (18), fc1 @72*512 (72),
// fc2 @144*512 (72). Total 216 KiB.
// ============================================================================
__global__ __launch_bounds__(256)
void prep_weights(const float* __restrict__ qkv_w, const float* __restrict__ proj_w,
                  const float* __restrict__ fc1_w, const float* __restrict__ fc2_w,
                  bf16* __restrict__ ws)
{
    const int t = blockIdx.x * 256 + threadIdx.x;
    const int f = t >> 6;
    const int lane = t & 63;
    const float* W; int KT, fr; bf16* dst;
    if (f < 54)       { W = qkv_w;  KT = 3;  fr = f;       dst = ws; }
    else if (f < 72)  { W = proj_w; KT = 3;  fr = f - 54;  dst = ws + 54*512; }
    else if (f < 144) { W = fc1_w;  KT = 3;  fr = f - 72;  dst = ws + 72*512; }
    else              { W = fc2_w;  KT = 12; fr = f - 144; dst = ws + 144*512; }
    const int nt = fr / KT, kt = fr % KT;
    const int Kin = KT * 32;
    const float* src = W + (nt*16 + (lane & 15))*Kin + kt*32 + 8*(lane >> 4);
    bf16* d = dst + fr*512 + lane*8;
    #pragma unroll
    for (int i = 0; i < 8; i++) d[i] = f2b(src[i]);
}

// ============================================================================
// Kernel A (MFMA): per-window LN1 + shifted-window attention + proj + residual.
// Block = 1 window (64 tokens), 4 waves; wave w owns token m-tile w (16 rows).
// Shift/partition/reverse folded into the gather offsets (tok_off).
// Per head: QKV (18 MFMA/wave; V computed TRANSPOSED via frag-as-A trick),
// S=QK^T (4), in-register softmax, PV (4). Then proj (18) + residual.
// C/D map: col=lane&15, row=(lane>>4)*4+reg (HW-verified by R3 pass).
// ============================================================================
__global__ __launch_bounds__(256)
void swin_attn_mfma(const float* __restrict__ x,
                    const float* __restrict__ ln1_w, const float* __restrict__ ln1_b,
                    const float* __restrict__ qkv_b, const float* __restrict__ proj_b,
                    const bf16* __restrict__ wsf,
                    float* __restrict__ x2)
{
    __shared__ int tok_off[64];
    __shared__ __align__(16) bf16 ln_s[64][104];  // pitch 208B
    __shared__ __align__(16) bf16 q_s[64][40];    // pitch 80B (q, scaled)
    __shared__ __align__(16) bf16 k_s[64][40];
    __shared__ __align__(16) bf16 vt_s[32][72];   // V transposed: [d][token]
    __shared__ __align__(16) bf16 p_s[64][72];    // probs (wave-private rows)
    __shared__ __align__(16) bf16 ao_s[64][104];  // attn out, all heads

    const int tid = threadIdx.x;
    const int win = blockIdx.x;
    const int b  = win >> 11;
    const int wd = (win >> 8) & 7;
    const int wh = (win >> 4) & 15;
    const int ww = win & 15;

    if (tid < 64) {
        const int n  = tid;
        const int df = (wd*4 + (n >> 4)       + 2) & 31;
        const int hf = (wh*4 + ((n >> 2) & 3) + 2) & 63;
        const int wf = (ww*4 + (n & 3)        + 2) & 63;
        tok_off[n] = (((b*32 + df)*64 + hf)*64 + wf) * 96;
    }
    __syncthreads();

    // ---- LN1: 4 lanes per token ----
    {
        const int lane = tid & 63;
        const int n    = (tid >> 6)*16 + (lane >> 2);
        const int sub  = lane & 3;
        const float4* xr4 = (const float4*)(x + tok_off[n] + sub*24);
        float4 va[6];
        float s = 0.f, ss = 0.f;
        #pragma unroll
        for (int i = 0; i < 6; i++) {
            va[i] = xr4[i];
            s  += va[i].x + va[i].y + va[i].z + va[i].w;
            ss += va[i].x*va[i].x + va[i].y*va[i].y + va[i].z*va[i].z + va[i].w*va[i].w;
        }
        s += __shfl_xor(s, 1); ss += __shfl_xor(ss, 1);
        s += __shfl_xor(s, 2); ss += __shfl_xor(ss, 2);
        const float mean = s * (1.f/96.f);
        const float var  = ss * (1.f/96.f) - mean*mean;
        const float inv  = rsqrtf(var + 1e-5f);
        #pragma unroll
        for (int i = 0; i < 6; i++) {
            const float vv[4] = {va[i].x, va[i].y, va[i].z, va[i].w};
            #pragma unroll
            for (int j2 = 0; j2 < 4; j2++) {
                const int c = sub*24 + i*4 + j2;
                ln_s[n][c] = f2b((vv[j2] - mean) * inv * ln1_w[c] + ln1_b[c]);
            }
        }
    }
    __syncthreads();

    const int w    = tid >> 6;
    const int lane = tid & 63;
    const int lc   = lane & 15;
    const int lr   = lane >> 4;
    const int m0   = w * 16;
    const int tokr = m0 + lr*4;
    const float scale = 0.17677669529663688f;

    // LN fragments for own m-tile: serve as A-frag (Q/K: rows=tokens) AND as
    // B-frag (Vt: B[c][token], n=lane&15=token) — identical loads.
    short8 lnA[3];
    #pragma unroll
    for (int kt = 0; kt < 3; kt++)
        lnA[kt] = *(const short8*)&ln_s[m0 + lc][kt*32 + 8*lr];

    for (int h = 0; h < 3; h++) {
        // ---- QKV (+ transposed V) ----
        #pragma unroll
        for (int nt2 = 0; nt2 < 2; nt2++) {
            const int dd = nt2*16 + lc;
            // q tile (n-tiles 2h, 2h+1)
            {
                f32x4 acc = {0.f,0.f,0.f,0.f};
                #pragma unroll
                for (int kt = 0; kt < 3; kt++)
                    acc = __builtin_amdgcn_mfma_f32_16x16x32_bf16(
                        lnA[kt], *(const short8*)(wsf + ((2*h+nt2)*3+kt)*512 + lane*8), acc, 0,0,0);
                const float bias = qkv_b[h*32 + dd];
                #pragma unroll
                for (int r = 0; r < 4; r++)
                    q_s[tokr + r][dd] = f2b((acc[r] + bias) * scale);
            }
            // k tile (n-tiles 6+2h, 7+2h)
            {
                f32x4 acc = {0.f,0.f,0.f,0.f};
                #pragma unroll
                for (int kt = 0; kt < 3; kt++)
                    acc = __builtin_amdgcn_mfma_f32_16x16x32_bf16(
                        lnA[kt], *(const short8*)(wsf + ((6+2*h+nt2)*3+kt)*512 + lane*8), acc, 0,0,0);
                const float bias = qkv_b[96 + h*32 + dd];
                #pragma unroll
                for (int r = 0; r < 4; r++)
                    k_s[tokr + r][dd] = f2b(acc[r] + bias);
            }
            // vt tile: A = Wv frag (rows=d), B = LN^T (cols=own 16 tokens)
            // D: row = d-local = lr*4+r, col = token-local = lc
            {
                f32x4 acc = {0.f,0.f,0.f,0.f};
                #pragma unroll
                for (int kt = 0; kt < 3; kt++)
                    acc = __builtin_amdgcn_mfma_f32_16x16x32_bf16(
                        *(const short8*)(wsf + ((12+2*h+nt2)*3+kt)*512 + lane*8), lnA[kt], acc, 0,0,0);
                #pragma unroll
                for (int r = 0; r < 4; r++) {
                    const int dl = nt2*16 + lr*4 + r;
                    vt_s[dl][m0 + lc] = f2b(acc[r] + qkv_b[192 + h*32 + dl]);
                }
            }
        }
        __syncthreads();

        // ---- S = q·k^T (4 tiles, K=32) + in-register softmax ----
        {
            const short8 qf = *(const short8*)&q_s[m0 + lc][8*lr];
            f32x4 sacc[4];
            #pragma unroll
            for (int nt = 0; nt < 4; nt++) {
                f32x4 z = {0.f,0.f,0.f,0.f};
                sacc[nt] = __builtin_amdgcn_mfma_f32_16x16x32_bf16(
                    qf, *(const short8*)&k_s[nt*16 + lc][8*lr], z, 0,0,0);
            }
            #pragma unroll
            for (int r = 0; r < 4; r++) {
                float mx = fmaxf(fmaxf(sacc[0][r], sacc[1][r]), fmaxf(sacc[2][r], sacc[3][r]));
                mx = fmaxf(mx, __shfl_xor(mx, 1));
                mx = fmaxf(mx, __shfl_xor(mx, 2));
                mx = fmaxf(mx, __shfl_xor(mx, 4));
                mx = fmaxf(mx, __shfl_xor(mx, 8));
                float e[4], sum = 0.f;
                #pragma unroll
                for (int nt = 0; nt < 4; nt++) { e[nt] = __expf(sacc[nt][r] - mx); sum += e[nt]; }
                sum += __shfl_xor(sum, 1);
                sum += __shfl_xor(sum, 2);
                sum += __shfl_xor(sum, 4);
                sum += __shfl_xor(sum, 8);
                const float rs = 1.f / sum;
                #pragma unroll
                for (int nt = 0; nt < 4; nt++)
                    p_s[tokr + r][nt*16 + lc] = f2b(e[nt] * rs);
            }
        }

        // ---- PV: A = P (own rows), B = vt rows (contiguous) ----
        {
            short8 pf[2];
            #pragma unroll
            for (int kt = 0; kt < 2; kt++)
                pf[kt] = *(const short8*)&p_s[m0 + lc][kt*32 + 8*lr];
            #pragma unroll
            for (int nt = 0; nt < 2; nt++) {
                f32x4 acc = {0.f,0.f,0.f,0.f};
                #pragma unroll
                for (int kt = 0; kt < 2; kt++)
                    acc = __builtin_amdgcn_mfma_f32_16x16x32_bf16(
                        pf[kt], *(const short8*)&vt_s[nt*16 + lc][kt*32 + 8*lr], acc, 0,0,0);
                #pragma unroll
                for (int r = 0; r < 4; r++)
                    ao_s[tokr + r][h*32 + nt*16 + lc] = f2b(acc[r]);
            }
        }
        __syncthreads();   // protect q/k/vt (+p) before next head overwrites
    }

    // ---- proj + bias + residual (ao rows are wave-local: no extra sync) ----
    {
        short8 af[3];
        #pragma unroll
        for (int kt = 0; kt < 3; kt++)
            af[kt] = *(const short8*)&ao_s[m0 + lc][kt*32 + 8*lr];
        const bf16* pw = wsf + 54*512;
        for (int nt = 0; nt < 6; nt++) {
            f32x4 acc = {0.f,0.f,0.f,0.f};
            #pragma unroll
            for (int kt = 0; kt < 3; kt++)
                acc = __builtin_amdgcn_mfma_f32_16x16x32_bf16(
                    af[kt], *(const short8*)(pw + (nt*3+kt)*512 + lane*8), acc, 0,0,0);
            const int c = nt*16 + lc;
            const float bias = proj_b[c];
            #pragma unroll
            for (int r = 0; r < 4; r++) {
                const int toff = tok_off[tokr + r];
                x2[toff + c] = x[toff + c] + acc[r] + bias;
            }
        }
    }
}

// ============================================================================
// Kernel B (MFMA): in-place LN2 + FC1 + exact GELU + FC2 + residual.
// (unchanged from R3 — validated, ~180 µs)
// ============================================================================
__global__ __launch_bounds__(256)
void swin_mlp_mfma(float* __restrict__ io,
                   const float* __restrict__ ln2_w, const float* __restrict__ ln2_b,
                   const float* __restrict__ fc1_b, const float* __restrict__ fc2_b,
                   const bf16* __restrict__ wsf)
{
    __shared__ __align__(16) bf16 ln2s[64][104];
    __shared__ __align__(16) bf16 hid[64][392];

    const int tid = threadIdx.x;
    const long long base = (long long)blockIdx.x * (64*96);
    const bf16* w1f = wsf + 72*512;
    const bf16* w2f = wsf + 144*512;

    {
        const int lane = tid & 63;
        const int n    = (tid >> 6)*16 + (lane >> 2);
        const int sub  = lane & 3;
        const float4* xr4 = (const float4*)(io + base + n*96 + sub*24);
        float4 va[6];
        float s = 0.f, ss = 0.f;
        #pragma unroll
        for (int i = 0; i < 6; i++) {
            va[i] = xr4[i];
            s  += va[i].x + va[i].y + va[i].z + va[i].w;
            ss += va[i].x*va[i].x + va[i].y*va[i].y + va[i].z*va[i].z + va[i].w*va[i].w;
        }
        s += __shfl_xor(s, 1); ss += __shfl_xor(ss, 1);
        s += __shfl_xor(s, 2); ss += __shfl_xor(ss, 2);
        const float mean = s * (1.f/96.f);
        const float var  = ss * (1.f/96.f) - mean*mean;
        const float inv  = rsqrtf(var + 1e-5f);
        #pragma unroll
        for (int i = 0; i < 6; i++) {
            const float vv[4] = {va[i].x, va[i].y, va[i].z, va[i].w};
            #pragma unroll
            for (int j2 = 0; j2 < 4; j2++) {
                const int c = sub*24 + i*4 + j2;
                ln2s[n][c] = f2b((vv[j2] - mean) * inv * ln2_w[c] + ln2_b[c]);
            }
        }
    }
    __syncthreads();

    const int w    = tid >> 6;
    const int lane = tid & 63;
    const int m0   = w * 16;
    const int lc   = lane & 15;
    const int lr   = lane >> 4;
    const int tokr = m0 + lr*4;

    {
        short8 afr[3];
        #pragma unroll
        for (int kt = 0; kt < 3; kt++)
            afr[kt] = *(const short8*)&ln2s[m0 + lc][kt*32 + 8*lr];

        for (int nt = 0; nt < 24; nt++) {
            f32x4 acc = {0.f, 0.f, 0.f, 0.f};
            #pragma unroll
            for (int kt = 0; kt < 3; kt++) {
                const short8 bfr = *(const short8*)(w1f + (nt*3 + kt)*512 + lane*8);
                acc = __builtin_amdgcn_mfma_f32_16x16x32_bf16(afr[kt], bfr, acc, 0, 0, 0);
            }
            const int j = nt*16 + lc;
            const float bias = fc1_b[j];
            #pragma unroll
            for (int r = 0; r < 4; r++)
                hid[tokr + r][j] = f2b(gelu_exact(acc[r] + bias));
        }
    }
    __syncthreads();

    {
        short8 afr[12];
        #pragma unroll
        for (int kt = 0; kt < 12; kt++)
            afr[kt] = *(const short8*)&hid[m0 + lc][kt*32 + 8*lr];

        for (int nt = 0; nt < 6; nt++) {
            f32x4 acc = {0.f, 0.f, 0.f, 0.f};
            #pragma unroll
            for (int kt = 0; kt < 12; kt++) {
                const short8 bfr = *(const short8*)(w2f + (nt*12 + kt)*512 + lane*8);
                acc = __builtin_amdgcn_mfma_f32_16x16x32_bf16(afr[kt], bfr, acc, 0, 0, 0);
            }
            const int j = nt*16 + lc;
            const float bias = fc2_b[j];
            #pragma unroll
            for (int r = 0; r < 4; r++) {
                const long long off = base + (long long)(tokr + r)*96 + j;
                io[off] = io[off] + acc[r] + bias;
            }
        }
    }
}

extern "C" void kernel_launch(void* const* d_in, const int* in_sizes, int n_in,
                              void* d_out, int out_size, void* d_ws, size_t ws_size,
                              hipStream_t stream)
{
    const float* x      = (const float*)d_in[0];
    const float* ln1_w  = (const float*)d_in[1];
    const float* ln1_b  = (const float*)d_in[2];
    const float* qkv_w  = (const float*)d_in[3];
    const float* qkv_b  = (const float*)d_in[4];
    const float* proj_w = (const float*)d_in[5];
    const float* proj_b = (const float*)d_in[6];
    const float* ln2_w  = (const float*)d_in[7];
    const float* ln2_b  = (const float*)d_in[8];
    const float* fc1_w  = (const float*)d_in[9];
    const float* fc1_b  = (const float*)d_in[10];
    const float* fc2_w  = (const float*)d_in[11];
    const float* fc2_b  = (const float*)d_in[12];
    float* out = (float*)d_out;
    bf16* wsf  = (bf16*)d_ws;   // 216 KiB

    prep_weights<<<54, 256, 0, stream>>>(qkv_w, proj_w, fc1_w, fc2_w, wsf);
    swin_attn_mfma<<<4096, 256, 0, stream>>>(x, ln1_w, ln1_b, qkv_b, proj_b, wsf, out);
    swin_mlp_mfma<<<4096, 256, 0, stream>>>(out, ln2_w, ln2_b, fc1_b, fc2_b, wsf);
}

// Round 5
// 341.738 us; speedup vs baseline: 31.0187x; 1.2529x over previous
//
#include <hip/hip_runtime.h>
#include <hip/hip_bf16.h>
#include <math.h>

typedef __hip_bfloat16 bf16;
using short8 = __attribute__((ext_vector_type(8))) short;
using f32x4  = __attribute__((ext_vector_type(4))) float;

__device__ __forceinline__ bf16 f2b(float v){ return __float2bfloat16(v); }
__device__ __forceinline__ float gelu_exact(float v){ return 0.5f * v * (1.f + erff(v * 0.70710678118654752f)); }

// ============================================================================
// Weight prep: fp32 weights -> bf16 fragment layout for mfma_f32_16x16x32_bf16.
// Fragment f=(nt,kt): lane l, elem i holds W[nt*16+(l&15)][kt*32+8*(l>>4)+i],
// at dst[f*512 + l*8 + i] (one contiguous 16B load per lane). Bits serve as
// B-frags (D = X·W^T) and A-frags (W rows as left operand) interchangeably.
// ws layout (bf16): qkv @0 (54), proj @54*512 (18), fc1 @72*512 (72),
// fc2 @144*512 (72). Total 216 KiB.
// ============================================================================
__global__ __launch_bounds__(256)
void prep_weights(const float* __restrict__ qkv_w, const float* __restrict__ proj_w,
                  const float* __restrict__ fc1_w, const float* __restrict__ fc2_w,
                  bf16* __restrict__ ws)
{
    const int t = blockIdx.x * 256 + threadIdx.x;
    const int f = t >> 6;
    const int lane = t & 63;
    const float* W; int KT, fr; bf16* dst;
    if (f < 54)       { W = qkv_w;  KT = 3;  fr = f;       dst = ws; }
    else if (f < 72)  { W = proj_w; KT = 3;  fr = f - 54;  dst = ws + 54*512; }
    else if (f < 144) { W = fc1_w;  KT = 3;  fr = f - 72;  dst = ws + 72*512; }
    else              { W = fc2_w;  KT = 12; fr = f - 144; dst = ws + 144*512; }
    const int nt = fr / KT, kt = fr % KT;
    const int Kin = KT * 32;
    const float* src = W + (nt*16 + (lane & 15))*Kin + kt*32 + 8*(lane >> 4);
    bf16* d = dst + fr*512 + lane*8;
    #pragma unroll
    for (int i = 0; i < 8; i++) d[i] = f2b(src[i]);
}

// ============================================================================
// FUSED kernel: per-window LN1 + shifted attention + proj + residual + LN2 +
// FC1 + GELU + FC2 + residual. Block = 1 window (64 tokens), 4 waves.
// After proj, x2 lives in registers (C-layout); LN2 stats via shfl over the
// 16 lc-lanes; FC2 output tiling == proj tiling so the final residual add is
// register-aligned. Single global write of the final output.
// LDS pool (50688 B) aliasing:
//   attn phase: ln_s | q_s | k_s | vt_s | p_s | ao_s
//   mlp  phase: ln2s == ao_s region (wave-local rows, no barrier);
//               hid (50176 B) == whole pool (one barrier after A-frag loads).
// 3 blocks/CU (LDS ~50.9 KB), target 3 waves/SIMD -> __launch_bounds__(256,3).
// ============================================================================
__global__ __launch_bounds__(256, 3)
void swin_fused(const float* __restrict__ x,
                const float* __restrict__ ln1_w, const float* __restrict__ ln1_b,
                const float* __restrict__ qkv_b, const float* __restrict__ proj_b,
                const float* __restrict__ ln2_w, const float* __restrict__ ln2_b,
                const float* __restrict__ fc1_b, const float* __restrict__ fc2_b,
                const bf16* __restrict__ wsf,
                float* __restrict__ out)
{
    __shared__ int tok_off[64];
    __shared__ __align__(16) char pool[50688];
    bf16 (*ln_s)[104] = (bf16(*)[104])(pool + 0);      // 13312 B
    bf16 (*q_s)[40]   = (bf16(*)[40])(pool + 13312);   //  5120 B
    bf16 (*k_s)[40]   = (bf16(*)[40])(pool + 18432);   //  5120 B
    bf16 (*vt_s)[72]  = (bf16(*)[72])(pool + 23552);   //  4608 B
    bf16 (*p_s)[72]   = (bf16(*)[72])(pool + 28160);   //  9216 B
    bf16 (*ao_s)[104] = (bf16(*)[104])(pool + 37376);  // 13312 B (end 50688)
    bf16 (*ln2s)[104] = ao_s;                          // alias (wave-local)
    bf16 (*hid)[392]  = (bf16(*)[392])(pool + 0);      // 50176 B (aliases all)

    const int tid = threadIdx.x;
    const int win = blockIdx.x;
    const int b  = win >> 11;
    const int wd = (win >> 8) & 7;
    const int wh = (win >> 4) & 15;
    const int ww = win & 15;

    if (tid < 64) {
        const int n  = tid;
        const int df = (wd*4 + (n >> 4)       + 2) & 31;
        const int hf = (wh*4 + ((n >> 2) & 3) + 2) & 63;
        const int wf = (ww*4 + (n & 3)        + 2) & 63;
        tok_off[n] = (((b*32 + df)*64 + hf)*64 + wf) * 96;
    }
    __syncthreads();

    // ---- LN1: 4 lanes per token ----
    {
        const int lane = tid & 63;
        const int n    = (tid >> 6)*16 + (lane >> 2);
        const int sub  = lane & 3;
        const float4* xr4 = (const float4*)(x + tok_off[n] + sub*24);
        float4 va[6];
        float s = 0.f, ss = 0.f;
        #pragma unroll
        for (int i = 0; i < 6; i++) {
            va[i] = xr4[i];
            s  += va[i].x + va[i].y + va[i].z + va[i].w;
            ss += va[i].x*va[i].x + va[i].y*va[i].y + va[i].z*va[i].z + va[i].w*va[i].w;
        }
        s += __shfl_xor(s, 1); ss += __shfl_xor(ss, 1);
        s += __shfl_xor(s, 2); ss += __shfl_xor(ss, 2);
        const float mean = s * (1.f/96.f);
        const float var  = ss * (1.f/96.f) - mean*mean;
        const float inv  = rsqrtf(var + 1e-5f);
        #pragma unroll
        for (int i = 0; i < 6; i++) {
            const float vv[4] = {va[i].x, va[i].y, va[i].z, va[i].w};
            #pragma unroll
            for (int j2 = 0; j2 < 4; j2++) {
                const int c = sub*24 + i*4 + j2;
                ln_s[n][c] = f2b((vv[j2] - mean) * inv * ln1_w[c] + ln1_b[c]);
            }
        }
    }
    __syncthreads();

    const int w    = tid >> 6;
    const int lane = tid & 63;
    const int lc   = lane & 15;
    const int lr   = lane >> 4;
    const int m0   = w * 16;
    const int tokr = m0 + lr*4;
    const float scale = 0.17677669529663688f;

    short8 lnA[3];
    #pragma unroll
    for (int kt = 0; kt < 3; kt++)
        lnA[kt] = *(const short8*)&ln_s[m0 + lc][kt*32 + 8*lr];

    // ================= attention (validated R4 structure) =================
    for (int h = 0; h < 3; h++) {
        #pragma unroll
        for (int nt2 = 0; nt2 < 2; nt2++) {
            const int dd = nt2*16 + lc;
            {
                f32x4 acc = {0.f,0.f,0.f,0.f};
                #pragma unroll
                for (int kt = 0; kt < 3; kt++)
                    acc = __builtin_amdgcn_mfma_f32_16x16x32_bf16(
                        lnA[kt], *(const short8*)(wsf + ((2*h+nt2)*3+kt)*512 + lane*8), acc, 0,0,0);
                const float bias = qkv_b[h*32 + dd];
                #pragma unroll
                for (int r = 0; r < 4; r++)
                    q_s[tokr + r][dd] = f2b((acc[r] + bias) * scale);
            }
            {
                f32x4 acc = {0.f,0.f,0.f,0.f};
                #pragma unroll
                for (int kt = 0; kt < 3; kt++)
                    acc = __builtin_amdgcn_mfma_f32_16x16x32_bf16(
                        lnA[kt], *(const short8*)(wsf + ((6+2*h+nt2)*3+kt)*512 + lane*8), acc, 0,0,0);
                const float bias = qkv_b[96 + h*32 + dd];
                #pragma unroll
                for (int r = 0; r < 4; r++)
                    k_s[tokr + r][dd] = f2b(acc[r] + bias);
            }
            {
                f32x4 acc = {0.f,0.f,0.f,0.f};
                #pragma unroll
                for (int kt = 0; kt < 3; kt++)
                    acc = __builtin_amdgcn_mfma_f32_16x16x32_bf16(
                        *(const short8*)(wsf + ((12+2*h+nt2)*3+kt)*512 + lane*8), lnA[kt], acc, 0,0,0);
                #pragma unroll
                for (int r = 0; r < 4; r++) {
                    const int dl = nt2*16 + lr*4 + r;
                    vt_s[dl][m0 + lc] = f2b(acc[r] + qkv_b[192 + h*32 + dl]);
                }
            }
        }
        __syncthreads();

        {
            const short8 qf = *(const short8*)&q_s[m0 + lc][8*lr];
            f32x4 sacc[4];
            #pragma unroll
            for (int nt = 0; nt < 4; nt++) {
                f32x4 z = {0.f,0.f,0.f,0.f};
                sacc[nt] = __builtin_amdgcn_mfma_f32_16x16x32_bf16(
                    qf, *(const short8*)&k_s[nt*16 + lc][8*lr], z, 0,0,0);
            }
            #pragma unroll
            for (int r = 0; r < 4; r++) {
                float mx = fmaxf(fmaxf(sacc[0][r], sacc[1][r]), fmaxf(sacc[2][r], sacc[3][r]));
                mx = fmaxf(mx, __shfl_xor(mx, 1));
                mx = fmaxf(mx, __shfl_xor(mx, 2));
                mx = fmaxf(mx, __shfl_xor(mx, 4));
                mx = fmaxf(mx, __shfl_xor(mx, 8));
                float e[4], sum = 0.f;
                #pragma unroll
                for (int nt = 0; nt < 4; nt++) { e[nt] = __expf(sacc[nt][r] - mx); sum += e[nt]; }
                sum += __shfl_xor(sum, 1);
                sum += __shfl_xor(sum, 2);
                sum += __shfl_xor(sum, 4);
                sum += __shfl_xor(sum, 8);
                const float rs = 1.f / sum;
                #pragma unroll
                for (int nt = 0; nt < 4; nt++)
                    p_s[tokr + r][nt*16 + lc] = f2b(e[nt] * rs);
            }
        }

        {
            short8 pf[2];
            #pragma unroll
            for (int kt = 0; kt < 2; kt++)
                pf[kt] = *(const short8*)&p_s[m0 + lc][kt*32 + 8*lr];
            #pragma unroll
            for (int nt = 0; nt < 2; nt++) {
                f32x4 acc = {0.f,0.f,0.f,0.f};
                #pragma unroll
                for (int kt = 0; kt < 2; kt++)
                    acc = __builtin_amdgcn_mfma_f32_16x16x32_bf16(
                        pf[kt], *(const short8*)&vt_s[nt*16 + lc][kt*32 + 8*lr], acc, 0,0,0);
                #pragma unroll
                for (int r = 0; r < 4; r++)
                    ao_s[tokr + r][h*32 + nt*16 + lc] = f2b(acc[r]);
            }
        }
        __syncthreads();
    }

    // ---- proj + bias + residual -> x2 kept in registers (C-layout) ----
    f32x4 xv[6];
    {
        short8 af[3];
        #pragma unroll
        for (int kt = 0; kt < 3; kt++)
            af[kt] = *(const short8*)&ao_s[m0 + lc][kt*32 + 8*lr];
        const bf16* pw = wsf + 54*512;
        #pragma unroll
        for (int nt = 0; nt < 6; nt++) {
            f32x4 acc = {0.f,0.f,0.f,0.f};
            #pragma unroll
            for (int kt = 0; kt < 3; kt++)
                acc = __builtin_amdgcn_mfma_f32_16x16x32_bf16(
                    af[kt], *(const short8*)(pw + (nt*3+kt)*512 + lane*8), acc, 0,0,0);
            const int c = nt*16 + lc;
            const float bias = proj_b[c];
            #pragma unroll
            for (int r = 0; r < 4; r++)
                xv[nt][r] = x[tok_off[tokr + r] + c] + acc[r] + bias;
        }
    }

    // ---- LN2 in registers; write A-frag layout into ln2s (== ao_s, wave-local) ----
    {
        float wl[6], bl[6];
        #pragma unroll
        for (int nt = 0; nt < 6; nt++) { wl[nt] = ln2_w[nt*16 + lc]; bl[nt] = ln2_b[nt*16 + lc]; }
        #pragma unroll
        for (int r = 0; r < 4; r++) {
            float s = 0.f, ss = 0.f;
            #pragma unroll
            for (int nt = 0; nt < 6; nt++) { const float v = xv[nt][r]; s += v; ss += v*v; }
            s += __shfl_xor(s, 1); ss += __shfl_xor(ss, 1);
            s += __shfl_xor(s, 2); ss += __shfl_xor(ss, 2);
            s += __shfl_xor(s, 4); ss += __shfl_xor(ss, 4);
            s += __shfl_xor(s, 8); ss += __shfl_xor(ss, 8);
            const float mean = s * (1.f/96.f);
            const float var  = ss * (1.f/96.f) - mean*mean;
            const float inv  = rsqrtf(var + 1e-5f);
            #pragma unroll
            for (int nt = 0; nt < 6; nt++)
                ln2s[tokr + r][nt*16 + lc] = f2b((xv[nt][r] - mean) * inv * wl[nt] + bl[nt]);
        }
    }

    // ---- FC1 A-frags, then barrier so hid may alias the whole pool ----
    short8 afr[3];
    #pragma unroll
    for (int kt = 0; kt < 3; kt++)
        afr[kt] = *(const short8*)&ln2s[m0 + lc][kt*32 + 8*lr];
    __syncthreads();

    // ---- FC1 + GELU -> hid (wave-local rows) ----
    {
        const bf16* w1f = wsf + 72*512;
        #pragma unroll
        for (int nt = 0; nt < 24; nt += 2) {
            short8 b0[3], b1[3];
            #pragma unroll
            for (int kt = 0; kt < 3; kt++) {
                b0[kt] = *(const short8*)(w1f + ((nt  )*3 + kt)*512 + lane*8);
                b1[kt] = *(const short8*)(w1f + ((nt+1)*3 + kt)*512 + lane*8);
            }
            f32x4 a0 = {0.f,0.f,0.f,0.f}, a1 = {0.f,0.f,0.f,0.f};
            #pragma unroll
            for (int kt = 0; kt < 3; kt++) {
                a0 = __builtin_amdgcn_mfma_f32_16x16x32_bf16(afr[kt], b0[kt], a0, 0,0,0);
                a1 = __builtin_amdgcn_mfma_f32_16x16x32_bf16(afr[kt], b1[kt], a1, 0,0,0);
            }
            const int j0 = nt*16 + lc;
            const float bi0 = fc1_b[j0], bi1 = fc1_b[j0 + 16];
            #pragma unroll
            for (int r = 0; r < 4; r++) {
                hid[tokr + r][j0]      = f2b(gelu_exact(a0[r] + bi0));
                hid[tokr + r][j0 + 16] = f2b(gelu_exact(a1[r] + bi1));
            }
        }
    }

    // ---- FC2 + bias + residual (x2 regs) -> single global write ----
    {
        short8 af2[12];
        #pragma unroll
        for (int kt = 0; kt < 12; kt++)
            af2[kt] = *(const short8*)&hid[m0 + lc][kt*32 + 8*lr];
        const bf16* w2f = wsf + 144*512;
        #pragma unroll
        for (int nt = 0; nt < 6; nt++) {
            f32x4 acc = {0.f,0.f,0.f,0.f};
            #pragma unroll
            for (int kt = 0; kt < 12; kt++)
                acc = __builtin_amdgcn_mfma_f32_16x16x32_bf16(
                    af2[kt], *(const short8*)(w2f + (nt*12 + kt)*512 + lane*8), acc, 0,0,0);
            const int c = nt*16 + lc;
            const float bias = fc2_b[c];
            #pragma unroll
            for (int r = 0; r < 4; r++)
                out[tok_off[tokr + r] + c] = xv[nt][r] + acc[r] + bias;
        }
    }
}

extern "C" void kernel_launch(void* const* d_in, const int* in_sizes, int n_in,
                              void* d_out, int out_size, void* d_ws, size_t ws_size,
                              hipStream_t stream)
{
    const float* x      = (const float*)d_in[0];
    const float* ln1_w  = (const float*)d_in[1];
    const float* ln1_b  = (const float*)d_in[2];
    const float* qkv_w  = (const float*)d_in[3];
    const float* qkv_b  = (const float*)d_in[4];
    const float* proj_w = (const float*)d_in[5];
    const float* proj_b = (const float*)d_in[6];
    const float* ln2_w  = (const float*)d_in[7];
    const float* ln2_b  = (const float*)d_in[8];
    const float* fc1_w  = (const float*)d_in[9];
    const float* fc1_b  = (const float*)d_in[10];
    const float* fc2_w  = (const float*)d_in[11];
    const float* fc2_b  = (const float*)d_in[12];
    float* out = (float*)d_out;
    bf16* wsf  = (bf16*)d_ws;   // 216 KiB

    prep_weights<<<54, 256, 0, stream>>>(qkv_w, proj_w, fc1_w, fc2_w, wsf);
    swin_fused<<<4096, 256, 0, stream>>>(x, ln1_w, ln1_b, qkv_b, proj_b,
                                         ln2_w, ln2_b, fc1_b, fc2_b, wsf, out);
}